// Round 9
// baseline (390.693 us; speedup 1.0000x reference)
//
#include <hip/hip_runtime.h>
#include <hip/hip_cooperative_groups.h>
#include <math.h>

namespace cg = cooperative_groups;

// TSMixerH: B=32,C=256,L=336,O=96,K=4,NL=2,DFF=1024
// Round 19:
//  - REVERT r18 overlap levers (a2-preload-early re-spilled: WRITE +17.7MB,
//    55->69us; idle-wave prefetch competed with compute-wave refills).
//  - NEW: single cooperative kernel mono = prep + grid.sync + mlp +
//    grid.sync + scatter. Rationale: (a) total - mlp == ~90us constant of
//    prep + launch/flush overhead, never attacked; (b) r16 proved L2 is
//    invalidated at every dispatch boundary, so the prep->mlp boundary
//    forces the 30.7MB cold refetch. Fusing removes 2 flushes + 2 launch
//    overheads, and prep work is redistributed cluster-locally (block bid
//    preps cluster (bid&7)>>1) so wbuf stays valid-clean in the READING
//    XCD's L2 across the fence (threadfence = agent release = wbl2;
//    write-once data, no reader caches a line pre-write -> no stale risk).
//  - Fallback: if hipLaunchCooperativeKernel errors (e.g. capture
//    unsupported), launch the proven r14 three-kernel path instead.

typedef unsigned short u16;
typedef unsigned int u32;
typedef unsigned long long u64;

constexpr int B = 32, C = 256, L = 336, O = 96, K = 4, NL = 2, DFF = 1024;
constexpr int TM = 32;
constexpr int NTILES = (B * C) / TM;  // 256
constexpr int LP = 352;               // L padded
constexpr int ZBS = 360;              // bf16 z row stride (u16)
constexpr int HS = 1032;              // bf16 H row stride (u16)

constexpr int DT1 = 32;  // phase-1 d-tiles (32-wide)
constexpr int KT1 = 22;  // phase-1 k-steps (16-deep over LP)
constexpr int LT2 = 11;  // phase-2 l-tiles (32-wide)
constexpr int KT2 = 64;  // phase-2 k-steps (16-deep over DFF)
constexpr int NTH = 6;   // head o-tiles (16x16 path)
constexpr int KSH = 11;  // head k-steps (32-deep)

constexpr int TS1 = KT1 * 512;  // 11264 u16 per d-tile
constexpr int TS2 = KT2 * 512;  // 32768 u16 per l-tile
constexpr int THS = KSH * 512;  // 5632 u16 per o-tile

constexpr int W1FRAGS = DT1 * KT1 * 64;  // 45056
constexpr int W2FRAGS = LT2 * KT2 * 64;  // 45056
constexpr int WHFRAGS = NTH * KSH * 64;  // 4224
constexpr int NW1 = W1FRAGS * K * NL;    // 360448
constexpr int NW2 = W2FRAGS * K * NL;    // 360448
constexpr int NPREP = 176 + 256 + 44 + 1;

typedef __bf16 bf16x8 __attribute__((ext_vector_type(8)));
typedef float f32x4 __attribute__((ext_vector_type(4)));
typedef float f32x16 __attribute__((ext_vector_type(16)));

// packed-channel staging for out (module-static: NOT in workspace)
__device__ float g_y[(size_t)B * O * C];

__device__ __forceinline__ u16 f2bf(float f) {
  union { float f; u32 u; } v;
  v.f = f;
  u32 r = v.u + 0x7fffu + ((v.u >> 16) & 1u);  // RNE
  return (u16)(r >> 16);
}
__device__ __forceinline__ float bf2f(u16 h) {
  union { u32 u; float f; } v;
  v.u = ((u32)h) << 16;
  return v.f;
}
__device__ __forceinline__ u32 pack2(float a, float b) {
  return (u32)f2bf(a) | ((u32)f2bf(b) << 16);
}

// ============================================================
// MONO: prep + mlp + scatter in one cooperative launch
// ============================================================
__global__ __launch_bounds__(1024, 4) void mono(
    const float* __restrict__ x, const float* __restrict__ rev_w,
    const float* __restrict__ rev_b, const float* __restrict__ W1,
    const float* __restrict__ b1, const float* __restrict__ W2,
    const float* __restrict__ b2, const float* __restrict__ Wh,
    const float* __restrict__ bh, const int* __restrict__ assign,
    int* __restrict__ meta, u16* __restrict__ wbuf,
    float* __restrict__ out) {
  __shared__ __align__(16) u16 zb[TM][ZBS];  // 23.0 KB
  __shared__ __align__(16) u16 Hsh[TM][HS];  // 66.0 KB
  __shared__ float s_mean[TM], s_std[TM], s_rw[TM], s_rb[TM];
  __shared__ int s_b[TM], s_p[TM];
  __shared__ int t_wcnt[4][K], t_pre[4][K], t_cofs[K + 1];

  const int bid = blockIdx.x;
  const int tid = threadIdx.x;
  const int wid = tid >> 6;  // 0..15
  const int lane = tid & 63;
  const int q = lane >> 4, rm = lane & 15;    // 16x16
  const int q2 = lane >> 5, n32 = lane & 31;  // 32x32

  // prep staging buffer aliases Hsh (phases are time-disjoint)
  u16(*sm)[516] = (u16(*)[516]) & Hsh[0][0];

  // ================= PHASE 1: prep (cluster-local) =================
  {
    const int xcd = bid & 7;
    const int cser = xcd >> 1;                      // cluster this block preps
    const int jj2 = ((xcd & 1) << 5) + (bid >> 3);  // 0..63 within cluster
    for (int t2 = 0; t2 < 2; ++t2) {
      const int iu = jj2 * 2 + t2;  // unit 0..118 in this cluster's list
      if (iu < 119) {
        __syncthreads();  // sm free (prev unit's emit done)
        if (iu < 44) {
          // ---- W1 unit ----
          const int dh = iu & 1;
          const int ks32 = (iu >> 1) % 11;
          const int kl = cser * 2 + iu / 22;
          for (int rr = 0; rr < 2; ++rr) {
            const int r = wid * 2 + rr;
            const int l = ks32 * 32 + r;
#pragma unroll
            for (int h = 0; h < 2; ++h) {
              const int cc = h * 256 + lane * 4;
              float4 v = make_float4(0.f, 0.f, 0.f, 0.f);
              if (l < L)
                v = *(const float4*)(W1 + ((size_t)kl * L + l) * DFF +
                                     dh * 512 + cc);
              uint2 p;
              p.x = pack2(v.x, v.y);
              p.y = pack2(v.z, v.w);
              *(uint2*)&sm[r][cc] = p;
            }
          }
          __syncthreads();
          for (int e = 0; e < 2; ++e) {
            const int item = wid * 2 + e;
            const int dtl = item >> 1, half = item & 1;
            const int rb = 16 * half + q2 * 8;
            const int col = dtl * 32 + n32;
            u32 w4[4];
#pragma unroll
            for (int t4 = 0; t4 < 4; ++t4)
              w4[t4] = (u32)sm[rb + 2 * t4][col] |
                       ((u32)sm[rb + 2 * t4 + 1][col] << 16);
            uint4 o;
            o.x = w4[0]; o.y = w4[1]; o.z = w4[2]; o.w = w4[3];
            const int dt = dh * 16 + dtl;
            const int ks = ks32 * 2 + half;
            *(uint4*)(wbuf + ((size_t)(kl * DT1 + dt) * KT1 + ks) * 512 +
                      lane * 8) = o;
          }
        } else if (iu < 108) {
          // ---- W2 unit ----
          const int i2 = iu - 44;
          const int ks32 = i2 & 31;
          const int kl = cser * 2 + (i2 >> 5);
          for (int rr = 0; rr < 2; ++rr) {
            const int r = wid * 2 + rr;
            const float* row = W2 + ((size_t)kl * DFF + ks32 * 32 + r) * L;
            {
              const int cc = lane * 4;
              const float4 v = *(const float4*)(row + cc);
              uint2 p;
              p.x = pack2(v.x, v.y);
              p.y = pack2(v.z, v.w);
              *(uint2*)&sm[r][cc] = p;
            }
            {
              const int cc = 256 + lane * 4;
              if (cc < 352) {
                float4 v = make_float4(0.f, 0.f, 0.f, 0.f);
                if (cc < L) v = *(const float4*)(row + cc);
                uint2 p;
                p.x = pack2(v.x, v.y);
                p.y = pack2(v.z, v.w);
                *(uint2*)&sm[r][cc] = p;
              }
            }
          }
          __syncthreads();
          for (int item = wid; item < 22; item += 16) {
            const int lt = item >> 1, half = item & 1;
            const int rb = 16 * half + q2 * 8;
            const int col = 32 * lt + n32;
            u32 w4[4];
#pragma unroll
            for (int t4 = 0; t4 < 4; ++t4)
              w4[t4] = (u32)sm[rb + 2 * t4][col] |
                       ((u32)sm[rb + 2 * t4 + 1][col] << 16);
            uint4 o;
            o.x = w4[0]; o.y = w4[1]; o.z = w4[2]; o.w = w4[3];
            const int ks = ks32 * 2 + half;
            *(uint4*)(wbuf + (size_t)NW1 * 8 +
                      ((size_t)(kl * LT2 + lt) * KT2 + ks) * 512 + lane * 8) =
                o;
          }
        } else {
          // ---- Wh unit ----
          const int ks = iu - 108;
          const int kk = cser;
          for (int rr = 0; rr < 2; ++rr) {
            const int r = wid * 2 + rr;
            const int l = ks * 32 + r;
            if (lane < 24) {
              const int cc = lane * 4;
              float4 v = make_float4(0.f, 0.f, 0.f, 0.f);
              if (l < L)
                v = *(const float4*)(Wh + ((size_t)kk * L + l) * O + cc);
              uint2 p;
              p.x = pack2(v.x, v.y);
              p.y = pack2(v.z, v.w);
              *(uint2*)&sm[r][cc] = p;
            }
          }
          __syncthreads();
          if (wid < NTH) {
            const int nt = wid;
            u32 w4[4];
#pragma unroll
            for (int t4 = 0; t4 < 4; ++t4) {
              const u16 aa = sm[q * 8 + 2 * t4][nt * 16 + rm];
              const u16 bb = sm[q * 8 + 2 * t4 + 1][nt * 16 + rm];
              w4[t4] = (u32)aa | ((u32)bb << 16);
            }
            uint4 o;
            o.x = w4[0]; o.y = w4[1]; o.z = w4[2]; o.w = w4[3];
            *(uint4*)(wbuf + (size_t)(NW1 + NW2) * 8 +
                      ((size_t)(kk * NTH + nt) * KSH + ks) * 512 + lane * 8) =
                o;
          }
        }
      }
    }
    // ---- table unit (one block) ----
    if (bid == NTILES - 1) {
      const int a = (tid < C) ? assign[tid] : 0;
      const u64 below = (1ull << lane) - 1ull;
      int myrank = 0;
      if (wid < 4) {
#pragma unroll
        for (int k = 0; k < K; ++k) {
          const u64 m = __ballot(a == k);
          if (a == k) myrank = (int)__popcll(m & below);
          if (lane == 0) t_wcnt[wid][k] = (int)__popcll(m);
        }
      }
      __syncthreads();
      if (tid == 0) {
        int tot[K];
        for (int k = 0; k < K; ++k) {
          int s = 0;
          for (int ww = 0; ww < 4; ++ww) {
            t_pre[ww][k] = s;
            s += t_wcnt[ww][k];
          }
          tot[k] = s;
        }
        t_cofs[0] = 0;
        for (int k = 0; k < K; ++k) t_cofs[k + 1] = t_cofs[k] + tot[k];
        for (int k = 0; k <= K; ++k) meta[512 + k] = t_cofs[k];
      }
      __syncthreads();
      if (tid < C) {
        const int pos = t_cofs[a] + t_pre[wid][a] + myrank;
        meta[256 + pos] = tid;  // chlist
        meta[520 + tid] = pos;  // ipos
        int k = 0;
        while (k < K - 1 && tid >= t_cofs[k + 1]) ++k;
        meta[tid] = (k << 16) | ((tid - t_cofs[k]) * TM);
      }
    }
  }
  __threadfence();  // agent release: write back dirty wbuf/meta L2 lines
  cg::this_grid().sync();

  // ================= PHASE 2: mlp (r14 body) =================
  const int swz = (bid & 7) * 32 + (bid >> 3);
  const int info = meta[swz];
  const int kcl = info >> 16;
  const int rstart = info & 0xffff;
  const int cofs = meta[512 + kcl];
  const int cnt = meta[512 + kcl + 1] - cofs;

  // RevIN: 2 rows per wave
  for (int i = 0; i < 2; ++i) {
    const int t = wid * 2 + i;
    const int ri = rstart + t;
    const int b = ri / cnt;
    const int c = meta[256 + cofs + (ri % cnt)];
    const float* xrow = x + (size_t)(b * C + c) * L;
    float v[6], s = 0.f, s2 = 0.f;
#pragma unroll
    for (int jj = 0; jj < 6; ++jj) {
      const int j = lane + jj * 64;
      v[jj] = (j < L) ? xrow[j] : 0.f;
      s += v[jj];
      s2 += v[jj] * v[jj];
    }
#pragma unroll
    for (int off = 32; off > 0; off >>= 1) {
      s += __shfl_down(s, off);
      s2 += __shfl_down(s2, off);
    }
    s = __shfl(s, 0);
    s2 = __shfl(s2, 0);
    const float mean = s * (1.f / L);
    const float var = s2 * (1.f / L) - mean * mean;
    const float stdv = sqrtf(var + 1e-5f);
    const float rstd = 1.f / stdv;
    const float rw = rev_w[c], rb_ = rev_b[c];
#pragma unroll
    for (int jj = 0; jj < 6; ++jj) {
      const int j = lane + jj * 64;
      if (j < L) zb[t][j] = f2bf((v[jj] - mean) * rstd * rw + rb_);
    }
    if (lane < LP - L) zb[t][L + lane] = 0;
    if (lane == 0) {
      s_mean[t] = mean;
      s_std[t] = stdv;
      s_rw[t] = rw;
      s_rb[t] = rb_;
      s_b[t] = b;
      s_p[t] = cofs + (ri % cnt);
    }
  }

  const u16* w1b = wbuf;
  const u16* w2b = wbuf + (size_t)NW1 * 8;
  const u16* whb = wbuf + (size_t)(NW1 + NW2) * 8;

  // preload layer-0 phase-1 ring
  bf16x8 a1[2][4];
  {
    const u16* b0 = w1b + (size_t)(kcl * NL) * W1FRAGS * 8 +
                    (size_t)(wid * 2) * TS1 + lane * 8;
#pragma unroll
    for (int t = 0; t < 2; ++t)
#pragma unroll
      for (int s = 0; s < 4; ++s)
        a1[t][s] = *(const bf16x8*)(b0 + (size_t)t * TS1 + s * 512);
  }
  __syncthreads();  // zb ready

  f32x16 zm;
#pragma unroll
  for (int i = 0; i < 16; ++i) zm[i] = 0.f;
  if (wid < LT2) {
#pragma unroll
    for (int g = 0; g < 4; ++g) {
      const uint2 zw = *(const uint2*)&zb[n32][32 * wid + 8 * g + 4 * q2];
      zm[4 * g + 0] = bf2f((u16)zw.x);
      zm[4 * g + 1] = bf2f((u16)(zw.x >> 16));
      zm[4 * g + 2] = bf2f((u16)zw.y);
      zm[4 * g + 3] = bf2f((u16)(zw.y >> 16));
    }
  }

  for (int l = 0; l < NL; ++l) {
    const int kl = kcl * NL + l;
    const u16* W1f = w1b + (size_t)kl * W1FRAGS * 8;
    const u16* W2f = w2b + (size_t)kl * W2FRAGS * 8;
    const float* b1p = b1 + kl * DFF;
    const float* b2p = b2 + kl * L;
    const u16* base1 = W1f + (size_t)(wid * 2) * TS1 + lane * 8;

    f32x16 acc[2];
#pragma unroll
    for (int t = 0; t < 2; ++t)
#pragma unroll
      for (int i = 0; i < 16; ++i) acc[t][i] = 0.f;
#pragma unroll
    for (int ks = 0; ks < KT1; ++ks) {
      const bf16x8 zf = *(const bf16x8*)&zb[n32][ks * 16 + q2 * 8];
#pragma unroll
      for (int t = 0; t < 2; ++t)
        acc[t] = __builtin_amdgcn_mfma_f32_32x32x16_bf16(a1[t][ks & 3], zf,
                                                         acc[t], 0, 0, 0);
      if (ks + 4 < KT1) {
#pragma unroll
        for (int t = 0; t < 2; ++t)
          a1[t][ks & 3] =
              *(const bf16x8*)(base1 + (size_t)t * TS1 + (ks + 4) * 512);
      }
    }
#pragma unroll
    for (int t = 0; t < 2; ++t) {
      const int dt = wid * 2 + t;
#pragma unroll
      for (int g = 0; g < 4; ++g) {
        const int db = dt * 32 + 8 * g + 4 * q2;
        const float4 bq = *(const float4*)(b1p + db);
        uint2 hw;
        hw.x = pack2(fmaxf(acc[t][4 * g + 0] + bq.x, 0.f),
                     fmaxf(acc[t][4 * g + 1] + bq.y, 0.f));
        hw.y = pack2(fmaxf(acc[t][4 * g + 2] + bq.z, 0.f),
                     fmaxf(acc[t][4 * g + 3] + bq.w, 0.f));
        *(uint2*)&Hsh[n32][db] = hw;
      }
    }

    bf16x8 a2[8];
    const u16* base2 = W2f + (size_t)wid * TS2 + lane * 8;
    if (wid < LT2) {
#pragma unroll
      for (int s = 0; s < 8; ++s)
        a2[s] = *(const bf16x8*)(base2 + s * 512);
    }
    __syncthreads();  // Hsh ready

    if (wid < LT2) {
#pragma unroll
      for (int ks = 0; ks < KT2; ++ks) {
        const bf16x8 hf = *(const bf16x8*)&Hsh[n32][ks * 16 + q2 * 8];
        zm = __builtin_amdgcn_mfma_f32_32x32x16_bf16(a2[ks & 7], hf, zm, 0, 0,
                                                     0);
        if (ks + 8 < KT2)
          a2[ks & 7] = *(const bf16x8*)(base2 + (ks + 8) * 512);
      }
#pragma unroll
      for (int g = 0; g < 4; ++g) {
        const int lc = 32 * wid + 8 * g + 4 * q2;
        if (lc < L) {
          const float4 bq = *(const float4*)(b2p + lc);
          zm[4 * g + 0] += bq.x;
          zm[4 * g + 1] += bq.y;
          zm[4 * g + 2] += bq.z;
          zm[4 * g + 3] += bq.w;
        }
        uint2 zw;
        zw.x = pack2(zm[4 * g + 0], zm[4 * g + 1]);
        zw.y = pack2(zm[4 * g + 2], zm[4 * g + 3]);
        *(uint2*)&zb[n32][lc] = zw;
      }
    }

    if (l + 1 < NL) {
      const u16* nb = w1b + (size_t)(kl + 1) * W1FRAGS * 8 +
                      (size_t)(wid * 2) * TS1 + lane * 8;
#pragma unroll
      for (int t = 0; t < 2; ++t)
#pragma unroll
        for (int s = 0; s < 4; ++s)
          a1[t][s] = *(const bf16x8*)(nb + (size_t)t * TS1 + s * 512);
    }
    __syncthreads();  // zb final for this layer
  }

  // head: g_y[b][o][p] = denorm(z @ Wh + bh), packed
  if (wid < NTH) {
    const u16* Whf =
        whb + (size_t)kcl * WHFRAGS * 8 + (size_t)wid * THS + lane * 8;
    f32x4 acc0 = {0.f, 0.f, 0.f, 0.f}, acc1 = {0.f, 0.f, 0.f, 0.f};
    for (int ks = 0; ks < KSH; ++ks) {
      const bf16x8 af = *(const bf16x8*)(Whf + ks * 512);
      const bf16x8 zf0 = *(const bf16x8*)&zb[rm][ks * 32 + q * 8];
      const bf16x8 zf1 = *(const bf16x8*)&zb[rm + 16][ks * 32 + q * 8];
      acc0 = __builtin_amdgcn_mfma_f32_16x16x32_bf16(af, zf0, acc0, 0, 0, 0);
      acc1 = __builtin_amdgcn_mfma_f32_16x16x32_bf16(af, zf1, acc1, 0, 0, 0);
    }
    const float4 bq = *(const float4*)(bh + kcl * O + wid * 16 + q * 4);
    const float bqa[4] = {bq.x, bq.y, bq.z, bq.w};
#pragma unroll
    for (int rg = 0; rg < 2; ++rg) {
      const int row = rm + 16 * rg;
      const float mean = s_mean[row], stdv = s_std[row];
      const float rw = s_rw[row], rb_ = s_rb[row];
      const int ob = s_b[row], pp = s_p[row];
      const f32x4 acc = rg ? acc1 : acc0;
#pragma unroll
      for (int gg = 0; gg < 4; ++gg) {
        const int o = wid * 16 + q * 4 + gg;
        const float v = acc[gg] + bqa[gg];
        g_y[((size_t)ob * O + o) * C + pp] = (v - rb_) / rw * stdv + mean;
      }
    }
  }
  __threadfence();  // release g_y
  cg::this_grid().sync();

  // ================= PHASE 3: scatter =================
  {
    int* sip = (int*)&zb[0][0];  // zb dead after head
    if (tid < C) sip[tid] = meta[520 + tid];
    __syncthreads();
    const int base = bid * 1024 + tid;
#pragma unroll
    for (int it = 0; it < 3; ++it) {
      const int idx = base + it * (NTILES * 1024);
      out[idx] = g_y[((size_t)(idx >> 8)) * C + sip[idx & 255]];
    }
  }
}

// ============================================================
// FALLBACK path: proven r14 three-kernel pipeline
// ============================================================
__global__ __launch_bounds__(256) void prep(const int* __restrict__ assign,
                                            const float* __restrict__ W1,
                                            const float* __restrict__ W2,
                                            const float* __restrict__ Wh,
                                            int* __restrict__ meta,
                                            u16* __restrict__ wbuf) {
  __shared__ u16 sm[32][516];
  const int bid = blockIdx.x;
  const int tid = threadIdx.x;
  const int wid = tid >> 6, lane = tid & 63;
  const int q = lane >> 4, rm = lane & 15;
  const int q2 = lane >> 5, n32 = lane & 31;

  if (bid < 176) {
    const int dh = bid & 1;
    const int ks32 = (bid >> 1) % 11;
    const int kl = bid / 22;
    for (int rr = 0; rr < 8; ++rr) {
      const int r = wid * 8 + rr;
      const int l = ks32 * 32 + r;
#pragma unroll
      for (int h = 0; h < 2; ++h) {
        const int c = h * 256 + lane * 4;
        float4 v = make_float4(0.f, 0.f, 0.f, 0.f);
        if (l < L)
          v = *(const float4*)(W1 + ((size_t)kl * L + l) * DFF + dh * 512 + c);
        uint2 p;
        p.x = pack2(v.x, v.y);
        p.y = pack2(v.z, v.w);
        *(uint2*)&sm[r][c] = p;
      }
    }
    __syncthreads();
    for (int e = 0; e < 8; ++e) {
      const int item = wid * 8 + e;
      const int dtl = item >> 1, half = item & 1;
      const int rb = 16 * half + q2 * 8;
      const int col = dtl * 32 + n32;
      uint4 o;
      u32 w4[4];
#pragma unroll
      for (int jj = 0; jj < 4; ++jj)
        w4[jj] =
            (u32)sm[rb + 2 * jj][col] | ((u32)sm[rb + 2 * jj + 1][col] << 16);
      o.x = w4[0]; o.y = w4[1]; o.z = w4[2]; o.w = w4[3];
      const int dt = dh * 16 + dtl;
      const int ks = ks32 * 2 + half;
      *(uint4*)(wbuf + ((size_t)(kl * DT1 + dt) * KT1 + ks) * 512 + lane * 8) =
          o;
    }
  } else if (bid < 432) {
    const int b2i = bid - 176;
    const int ks32 = b2i & 31;
    const int kl = b2i >> 5;
    for (int rr = 0; rr < 8; ++rr) {
      const int r = wid * 8 + rr;
      const float* row = W2 + ((size_t)kl * DFF + ks32 * 32 + r) * L;
      {
        const int c = lane * 4;
        const float4 v = *(const float4*)(row + c);
        uint2 p;
        p.x = pack2(v.x, v.y);
        p.y = pack2(v.z, v.w);
        *(uint2*)&sm[r][c] = p;
      }
      {
        const int c = 256 + lane * 4;
        if (c < 352) {
          float4 v = make_float4(0.f, 0.f, 0.f, 0.f);
          if (c < L) v = *(const float4*)(row + c);
          uint2 p;
          p.x = pack2(v.x, v.y);
          p.y = pack2(v.z, v.w);
          *(uint2*)&sm[r][c] = p;
        }
      }
    }
    __syncthreads();
    for (int item = wid; item < 22; item += 4) {
      const int lt = item >> 1, half = item & 1;
      const int rb = 16 * half + q2 * 8;
      const int col = 32 * lt + n32;
      uint4 o;
      u32 w4[4];
#pragma unroll
      for (int jj = 0; jj < 4; ++jj)
        w4[jj] =
            (u32)sm[rb + 2 * jj][col] | ((u32)sm[rb + 2 * jj + 1][col] << 16);
      o.x = w4[0]; o.y = w4[1]; o.z = w4[2]; o.w = w4[3];
      const int ks = ks32 * 2 + half;
      *(uint4*)(wbuf + (size_t)NW1 * 8 +
                ((size_t)(kl * LT2 + lt) * KT2 + ks) * 512 + lane * 8) = o;
    }
  } else if (bid < 476) {
    const int b3i = bid - 432;
    const int ks = b3i % 11;
    const int kk = b3i / 11;
    for (int rr = 0; rr < 8; ++rr) {
      const int r = wid * 8 + rr;
      const int l = ks * 32 + r;
      if (lane < 24) {
        const int c = lane * 4;
        float4 v = make_float4(0.f, 0.f, 0.f, 0.f);
        if (l < L) v = *(const float4*)(Wh + ((size_t)kk * L + l) * O + c);
        uint2 p;
        p.x = pack2(v.x, v.y);
        p.y = pack2(v.z, v.w);
        *(uint2*)&sm[r][c] = p;
      }
    }
    __syncthreads();
    for (int nt = wid; nt < NTH; nt += 4) {
      uint4 o;
      u32 w4[4];
#pragma unroll
      for (int jj = 0; jj < 4; ++jj) {
        const u16 a = sm[q * 8 + 2 * jj][nt * 16 + rm];
        const u16 b = sm[q * 8 + 2 * jj + 1][nt * 16 + rm];
        w4[jj] = (u32)a | ((u32)b << 16);
      }
      o.x = w4[0]; o.y = w4[1]; o.z = w4[2]; o.w = w4[3];
      *(uint4*)(wbuf + (size_t)(NW1 + NW2) * 8 +
                ((size_t)(kk * NTH + nt) * KSH + ks) * 512 + lane * 8) = o;
    }
  } else {
    __shared__ int wcnt[4][K];
    __shared__ int pre[4][K];
    __shared__ int cofs[K + 1];
    const int a = assign[tid];
    const u64 below = (1ull << lane) - 1ull;
    int myrank = 0;
#pragma unroll
    for (int k = 0; k < K; ++k) {
      const u64 m = __ballot(a == k);
      if (a == k) myrank = (int)__popcll(m & below);
      if (lane == 0) wcnt[wid][k] = (int)__popcll(m);
    }
    __syncthreads();
    if (tid == 0) {
      int tot[K];
      for (int k = 0; k < K; ++k) {
        int s = 0;
        for (int ww = 0; ww < 4; ++ww) {
          pre[ww][k] = s;
          s += wcnt[ww][k];
        }
        tot[k] = s;
      }
      cofs[0] = 0;
      for (int k = 0; k < K; ++k) cofs[k + 1] = cofs[k] + tot[k];
      for (int k = 0; k <= K; ++k) meta[512 + k] = cofs[k];
    }
    __syncthreads();
    const int pos = cofs[a] + pre[wid][a] + myrank;
    meta[256 + pos] = tid;
    meta[520 + tid] = pos;
    int k = 0;
    while (k < K - 1 && tid >= cofs[k + 1]) ++k;
    meta[tid] = (k << 16) | ((tid - cofs[k]) * TM);
  }
}

__global__ __launch_bounds__(1024, 4) void mlp_mfma(
    const float* __restrict__ x, const float* __restrict__ rev_w,
    const float* __restrict__ rev_b, const float* __restrict__ b1,
    const float* __restrict__ b2, const float* __restrict__ bh,
    const int* __restrict__ meta, const u16* __restrict__ wbuf) {
  __shared__ __align__(16) u16 zb[TM][ZBS];
  __shared__ __align__(16) u16 Hsh[TM][HS];
  __shared__ float s_mean[TM], s_std[TM], s_rw[TM], s_rb[TM];
  __shared__ int s_b[TM], s_p[TM];

  const int tid = threadIdx.x;
  const int wid = tid >> 6;
  const int lane = tid & 63;
  const int q = lane >> 4, rm = lane & 15;
  const int q2 = lane >> 5, n32 = lane & 31;

  const int swz = (blockIdx.x & 7) * 32 + (blockIdx.x >> 3);
  const int info = meta[swz];
  const int kcl = info >> 16;
  const int rstart = info & 0xffff;
  const int cofs = meta[512 + kcl];
  const int cnt = meta[512 + kcl + 1] - cofs;

  for (int i = 0; i < 2; ++i) {
    const int t = wid * 2 + i;
    const int ri = rstart + t;
    const int b = ri / cnt;
    const int c = meta[256 + cofs + (ri % cnt)];
    const float* xrow = x + (size_t)(b * C + c) * L;
    float v[6], s = 0.f, s2 = 0.f;
#pragma unroll
    for (int jj = 0; jj < 6; ++jj) {
      const int j = lane + jj * 64;
      v[jj] = (j < L) ? xrow[j] : 0.f;
      s += v[jj];
      s2 += v[jj] * v[jj];
    }
#pragma unroll
    for (int off = 32; off > 0; off >>= 1) {
      s += __shfl_down(s, off);
      s2 += __shfl_down(s2, off);
    }
    s = __shfl(s, 0);
    s2 = __shfl(s2, 0);
    const float mean = s * (1.f / L);
    const float var = s2 * (1.f / L) - mean * mean;
    const float stdv = sqrtf(var + 1e-5f);
    const float rstd = 1.f / stdv;
    const float rw = rev_w[c], rb_ = rev_b[c];
#pragma unroll
    for (int jj = 0; jj < 6; ++jj) {
      const int j = lane + jj * 64;
      if (j < L) zb[t][j] = f2bf((v[jj] - mean) * rstd * rw + rb_);
    }
    if (lane < LP - L) zb[t][L + lane] = 0;
    if (lane == 0) {
      s_mean[t] = mean;
      s_std[t] = stdv;
      s_rw[t] = rw;
      s_rb[t] = rb_;
      s_b[t] = b;
      s_p[t] = cofs + (ri % cnt);
    }
  }

  const u16* w1b = wbuf;
  const u16* w2b = wbuf + (size_t)NW1 * 8;
  const u16* whb = wbuf + (size_t)(NW1 + NW2) * 8;

  bf16x8 a1[2][4];
  {
    const u16* b0 = w1b + (size_t)(kcl * NL) * W1FRAGS * 8 +
                    (size_t)(wid * 2) * TS1 + lane * 8;
#pragma unroll
    for (int t = 0; t < 2; ++t)
#pragma unroll
      for (int s = 0; s < 4; ++s)
        a1[t][s] = *(const bf16x8*)(b0 + (size_t)t * TS1 + s * 512);
  }
  __syncthreads();

  f32x16 zm;
#pragma unroll
  for (int i = 0; i < 16; ++i) zm[i] = 0.f;
  if (wid < LT2) {
#pragma unroll
    for (int g = 0; g < 4; ++g) {
      const uint2 zw = *(const uint2*)&zb[n32][32 * wid + 8 * g + 4 * q2];
      zm[4 * g + 0] = bf2f((u16)zw.x);
      zm[4 * g + 1] = bf2f((u16)(zw.x >> 16));
      zm[4 * g + 2] = bf2f((u16)zw.y);
      zm[4 * g + 3] = bf2f((u16)(zw.y >> 16));
    }
  }

  for (int l = 0; l < NL; ++l) {
    const int kl = kcl * NL + l;
    const u16* W1f = w1b + (size_t)kl * W1FRAGS * 8;
    const u16* W2f = w2b + (size_t)kl * W2FRAGS * 8;
    const float* b1p = b1 + kl * DFF;
    const float* b2p = b2 + kl * L;
    const u16* base1 = W1f + (size_t)(wid * 2) * TS1 + lane * 8;

    f32x16 acc[2];
#pragma unroll
    for (int t = 0; t < 2; ++t)
#pragma unroll
      for (int i = 0; i < 16; ++i) acc[t][i] = 0.f;
#pragma unroll
    for (int ks = 0; ks < KT1; ++ks) {
      const bf16x8 zf = *(const bf16x8*)&zb[n32][ks * 16 + q2 * 8];
#pragma unroll
      for (int t = 0; t < 2; ++t)
        acc[t] = __builtin_amdgcn_mfma_f32_32x32x16_bf16(a1[t][ks & 3], zf,
                                                         acc[t], 0, 0, 0);
      if (ks + 4 < KT1) {
#pragma unroll
        for (int t = 0; t < 2; ++t)
          a1[t][ks & 3] =
              *(const bf16x8*)(base1 + (size_t)t * TS1 + (ks + 4) * 512);
      }
    }
#pragma unroll
    for (int t = 0; t < 2; ++t) {
      const int dt = wid * 2 + t;
#pragma unroll
      for (int g = 0; g < 4; ++g) {
        const int db = dt * 32 + 8 * g + 4 * q2;
        const float4 bq = *(const float4*)(b1p + db);
        uint2 hw;
        hw.x = pack2(fmaxf(acc[t][4 * g + 0] + bq.x, 0.f),
                     fmaxf(acc[t][4 * g + 1] + bq.y, 0.f));
        hw.y = pack2(fmaxf(acc[t][4 * g + 2] + bq.z, 0.f),
                     fmaxf(acc[t][4 * g + 3] + bq.w, 0.f));
        *(uint2*)&Hsh[n32][db] = hw;
      }
    }

    bf16x8 a2[8];
    const u16* base2 = W2f + (size_t)wid * TS2 + lane * 8;
    if (wid < LT2) {
#pragma unroll
      for (int s = 0; s < 8; ++s) a2[s] = *(const bf16x8*)(base2 + s * 512);
    }
    __syncthreads();

    if (wid < LT2) {
#pragma unroll
      for (int ks = 0; ks < KT2; ++ks) {
        const bf16x8 hf = *(const bf16x8*)&Hsh[n32][ks * 16 + q2 * 8];
        zm = __builtin_amdgcn_mfma_f32_32x32x16_bf16(a2[ks & 7], hf, zm, 0, 0,
                                                     0);
        if (ks + 8 < KT2)
          a2[ks & 7] = *(const bf16x8*)(base2 + (ks + 8) * 512);
      }
#pragma unroll
      for (int g = 0; g < 4; ++g) {
        const int lc = 32 * wid + 8 * g + 4 * q2;
        if (lc < L) {
          const float4 bq = *(const float4*)(b2p + lc);
          zm[4 * g + 0] += bq.x;
          zm[4 * g + 1] += bq.y;
          zm[4 * g + 2] += bq.z;
          zm[4 * g + 3] += bq.w;
        }
        uint2 zw;
        zw.x = pack2(zm[4 * g + 0], zm[4 * g + 1]);
        zw.y = pack2(zm[4 * g + 2], zm[4 * g + 3]);
        *(uint2*)&zb[n32][lc] = zw;
      }
    }

    if (l + 1 < NL) {
      const u16* nb = w1b + (size_t)(kl + 1) * W1FRAGS * 8 +
                      (size_t)(wid * 2) * TS1 + lane * 8;
#pragma unroll
      for (int t = 0; t < 2; ++t)
#pragma unroll
        for (int s = 0; s < 4; ++s)
          a1[t][s] = *(const bf16x8*)(nb + (size_t)t * TS1 + s * 512);
    }
    __syncthreads();
  }

  if (wid < NTH) {
    const u16* Whf =
        whb + (size_t)kcl * WHFRAGS * 8 + (size_t)wid * THS + lane * 8;
    f32x4 acc0 = {0.f, 0.f, 0.f, 0.f}, acc1 = {0.f, 0.f, 0.f, 0.f};
    for (int ks = 0; ks < KSH; ++ks) {
      const bf16x8 af = *(const bf16x8*)(Whf + ks * 512);
      const bf16x8 zf0 = *(const bf16x8*)&zb[rm][ks * 32 + q * 8];
      const bf16x8 zf1 = *(const bf16x8*)&zb[rm + 16][ks * 32 + q * 8];
      acc0 = __builtin_amdgcn_mfma_f32_16x16x32_bf16(af, zf0, acc0, 0, 0, 0);
      acc1 = __builtin_amdgcn_mfma_f32_16x16x32_bf16(af, zf1, acc1, 0, 0, 0);
    }
    const float4 bq = *(const float4*)(bh + kcl * O + wid * 16 + q * 4);
    const float bqa[4] = {bq.x, bq.y, bq.z, bq.w};
#pragma unroll
    for (int rg = 0; rg < 2; ++rg) {
      const int row = rm + 16 * rg;
      const float mean = s_mean[row], stdv = s_std[row];
      const float rw = s_rw[row], rb_ = s_rb[row];
      const int ob = s_b[row], pp = s_p[row];
      const f32x4 acc = rg ? acc1 : acc0;
#pragma unroll
      for (int gg = 0; gg < 4; ++gg) {
        const int o = wid * 16 + q * 4 + gg;
        const float v = acc[gg] + bqa[gg];
        g_y[((size_t)ob * O + o) * C + pp] = (v - rb_) / rw * stdv + mean;
      }
    }
  }
}

__global__ __launch_bounds__(1024) void scatter_out(
    const int* __restrict__ meta, float* __restrict__ out) {
  const int row = blockIdx.x * 4 + (threadIdx.x >> 8);
  const int c = threadIdx.x & 255;
  const int p = meta[520 + c];
  out[(size_t)row * C + c] = g_y[(size_t)row * C + p];
}

extern "C" void kernel_launch(void* const* d_in, const int* in_sizes, int n_in,
                              void* d_out, int out_size, void* d_ws,
                              size_t ws_size, hipStream_t stream) {
  const float* x = (const float*)d_in[0];
  const float* rev_w = (const float*)d_in[1];
  const float* rev_b = (const float*)d_in[2];
  const float* W1 = (const float*)d_in[3];
  const float* b1 = (const float*)d_in[4];
  const float* W2 = (const float*)d_in[5];
  const float* b2 = (const float*)d_in[6];
  const float* Wh = (const float*)d_in[7];
  const float* bh = (const float*)d_in[8];
  const int* assign = (const int*)d_in[9];
  float* out = (float*)d_out;

  int* meta = (int*)d_ws;                  // ~3.1 KB
  u16* wbuf = (u16*)((char*)d_ws + 4096);  // 11.6 MB bf16 fragments

  void* kargs[] = {(void*)&x,    (void*)&rev_w, (void*)&rev_b, (void*)&W1,
                   (void*)&b1,   (void*)&W2,    (void*)&b2,    (void*)&Wh,
                   (void*)&bh,   (void*)&assign, (void*)&meta, (void*)&wbuf,
                   (void*)&out};
  hipError_t e = hipLaunchCooperativeKernel(mono, dim3(NTILES), dim3(1024),
                                            kargs, 0, stream);
  if (e != hipSuccess) {
    (void)hipGetLastError();  // clear
    prep<<<NPREP, 256, 0, stream>>>(assign, W1, W2, Wh, meta, wbuf);
    mlp_mfma<<<NTILES, 1024, 0, stream>>>(x, rev_w, rev_b, b1, b2, bh, meta,
                                          wbuf);
    scatter_out<<<(B * O) / 4, 1024, 0, stream>>>(meta, out);
  }
}

// Round 10
// 155.376 us; speedup vs baseline: 2.5145x; 2.5145x over previous
//
#include <hip/hip_runtime.h>
#include <math.h>

// TSMixerH: B=32,C=256,L=336,O=96,K=4,NL=2,DFF=1024
// Round 20:
//  - DROP r19 mono (310us: cooperative path pathological under this
//    harness; 131 GB/s idle body). Key yield: bench carries ~80us FIXED
//    non-kernel overhead (390-310). Addressable GPU time = mlp 55 +
//    prep ~7 + scatter ~3. Only mlp matters.
//  - Lever: modest ring deepening within the VGPR budget. r15's spill
//    was D1=6 AND D2=16 together (a2 alone = 64 regs). Phase-2 live set
//    is only zm(16)+a2+addr (acc/a1 dead) -> D2=12 (48 regs) fits;
//    phase-1 live a1(40)+acc(32)+zm(16) ~ 100 < 128 -> D1=5 fits.
//    Window: ph1 128->160 KB, ph2 88->132 KB => front rate +25-50%.
//  - Plus r18's zero-cost L1 lever: a1 preload BEFORE RevIN (front
//    starts at t=0, overlaps x reads; no extra live regs).
//  - KEEP r14 packed-y + scatter_out. Tripwires: WRITE>30MB or VGPR
//    pinned 64 with dur up => spill => revert depths.

typedef unsigned short u16;
typedef unsigned int u32;
typedef unsigned long long u64;

constexpr int B = 32, C = 256, L = 336, O = 96, K = 4, NL = 2, DFF = 1024;
constexpr int TM = 32;
constexpr int NTILES = (B * C) / TM;  // 256
constexpr int LP = 352;               // L padded
constexpr int ZBS = 360;              // bf16 z row stride (u16)
constexpr int HS = 1032;              // bf16 H row stride (u16)

constexpr int DT1 = 32;  // phase-1 d-tiles (32-wide)
constexpr int KT1 = 22;  // phase-1 k-steps (16-deep over LP)
constexpr int LT2 = 11;  // phase-2 l-tiles (32-wide)
constexpr int KT2 = 64;  // phase-2 k-steps (16-deep over DFF)
constexpr int NTH = 6;   // head o-tiles (16x16 path)
constexpr int KSH = 11;  // head k-steps (32-deep)

constexpr int D1 = 5;   // phase-1 ring depth (r14: 4)
constexpr int D2 = 12;  // phase-2 ring depth (r14: 8)

constexpr int TS1 = KT1 * 512;  // 11264 u16 per d-tile
constexpr int TS2 = KT2 * 512;  // 32768 u16 per l-tile
constexpr int THS = KSH * 512;  // 5632 u16 per o-tile

constexpr int W1FRAGS = DT1 * KT1 * 64;  // 45056
constexpr int W2FRAGS = LT2 * KT2 * 64;  // 45056
constexpr int WHFRAGS = NTH * KSH * 64;  // 4224
constexpr int NW1 = W1FRAGS * K * NL;    // 360448
constexpr int NW2 = W2FRAGS * K * NL;    // 360448
constexpr int NPREP = 176 + 256 + 44 + 1;

typedef __bf16 bf16x8 __attribute__((ext_vector_type(8)));
typedef float f32x4 __attribute__((ext_vector_type(4)));
typedef float f32x16 __attribute__((ext_vector_type(16)));

// packed-channel staging for out (module-static: NOT in workspace)
__device__ float g_y[(size_t)B * O * C];

__device__ __forceinline__ u16 f2bf(float f) {
  union { float f; u32 u; } v;
  v.f = f;
  u32 r = v.u + 0x7fffu + ((v.u >> 16) & 1u);  // RNE
  return (u16)(r >> 16);
}
__device__ __forceinline__ float bf2f(u16 h) {
  union { u32 u; float f; } v;
  v.u = ((u32)h) << 16;
  return v.f;
}
__device__ __forceinline__ u32 pack2(float a, float b) {
  return (u32)f2bf(a) | ((u32)f2bf(b) << 16);
}

// ---- merged prep: repacks (blocks 0..475) + tables (block 476) ----
__global__ __launch_bounds__(256) void prep(const int* __restrict__ assign,
                                            const float* __restrict__ W1,
                                            const float* __restrict__ W2,
                                            const float* __restrict__ Wh,
                                            int* __restrict__ meta,
                                            u16* __restrict__ wbuf) {
  __shared__ u16 sm[32][516];
  const int bid = blockIdx.x;
  const int tid = threadIdx.x;
  const int wid = tid >> 6, lane = tid & 63;
  const int q = lane >> 4, rm = lane & 15;    // 16x16 emit (head)
  const int q2 = lane >> 5, n32 = lane & 31;  // 32x32 emit

  if (bid < 176) {  // ---- W1 ----
    const int dh = bid & 1;
    const int ks32 = (bid >> 1) % 11;
    const int kl = bid / 22;
    for (int rr = 0; rr < 8; ++rr) {
      const int r = wid * 8 + rr;
      const int l = ks32 * 32 + r;
#pragma unroll
      for (int h = 0; h < 2; ++h) {
        const int c = h * 256 + lane * 4;
        float4 v = make_float4(0.f, 0.f, 0.f, 0.f);
        if (l < L)
          v = *(const float4*)(W1 + ((size_t)kl * L + l) * DFF + dh * 512 + c);
        uint2 p;
        p.x = pack2(v.x, v.y);
        p.y = pack2(v.z, v.w);
        *(uint2*)&sm[r][c] = p;
      }
    }
    __syncthreads();
    for (int e = 0; e < 8; ++e) {
      const int item = wid * 8 + e;
      const int dtl = item >> 1, half = item & 1;
      const int rb = 16 * half + q2 * 8;
      const int col = dtl * 32 + n32;
      uint4 o;
      u32 w4[4];
#pragma unroll
      for (int jj = 0; jj < 4; ++jj)
        w4[jj] = (u32)sm[rb + 2 * jj][col] | ((u32)sm[rb + 2 * jj + 1][col] << 16);
      o.x = w4[0]; o.y = w4[1]; o.z = w4[2]; o.w = w4[3];
      const int dt = dh * 16 + dtl;
      const int ks = ks32 * 2 + half;
      *(uint4*)(wbuf + ((size_t)(kl * DT1 + dt) * KT1 + ks) * 512 + lane * 8) = o;
    }
  } else if (bid < 432) {  // ---- W2 ----
    const int b2i = bid - 176;
    const int ks32 = b2i & 31;
    const int kl = b2i >> 5;
    for (int rr = 0; rr < 8; ++rr) {
      const int r = wid * 8 + rr;
      const float* row = W2 + ((size_t)kl * DFF + ks32 * 32 + r) * L;
      {
        const int c = lane * 4;
        const float4 v = *(const float4*)(row + c);
        uint2 p;
        p.x = pack2(v.x, v.y);
        p.y = pack2(v.z, v.w);
        *(uint2*)&sm[r][c] = p;
      }
      {
        const int c = 256 + lane * 4;
        if (c < 352) {
          float4 v = make_float4(0.f, 0.f, 0.f, 0.f);
          if (c < L) v = *(const float4*)(row + c);
          uint2 p;
          p.x = pack2(v.x, v.y);
          p.y = pack2(v.z, v.w);
          *(uint2*)&sm[r][c] = p;
        }
      }
    }
    __syncthreads();
    for (int item = wid; item < 22; item += 4) {
      const int lt = item >> 1, half = item & 1;
      const int rb = 16 * half + q2 * 8;
      const int col = 32 * lt + n32;
      uint4 o;
      u32 w4[4];
#pragma unroll
      for (int jj = 0; jj < 4; ++jj)
        w4[jj] = (u32)sm[rb + 2 * jj][col] | ((u32)sm[rb + 2 * jj + 1][col] << 16);
      o.x = w4[0]; o.y = w4[1]; o.z = w4[2]; o.w = w4[3];
      const int ks = ks32 * 2 + half;
      *(uint4*)(wbuf + (size_t)NW1 * 8 +
                ((size_t)(kl * LT2 + lt) * KT2 + ks) * 512 + lane * 8) = o;
    }
  } else if (bid < 476) {  // ---- Wh ----
    const int b3i = bid - 432;
    const int ks = b3i % 11;
    const int kk = b3i / 11;
    for (int rr = 0; rr < 8; ++rr) {
      const int r = wid * 8 + rr;
      const int l = ks * 32 + r;
      if (lane < 24) {
        const int c = lane * 4;
        float4 v = make_float4(0.f, 0.f, 0.f, 0.f);
        if (l < L) v = *(const float4*)(Wh + ((size_t)kk * L + l) * O + c);
        uint2 p;
        p.x = pack2(v.x, v.y);
        p.y = pack2(v.z, v.w);
        *(uint2*)&sm[r][c] = p;
      }
    }
    __syncthreads();
    for (int nt = wid; nt < NTH; nt += 4) {
      uint4 o;
      u32 w4[4];
#pragma unroll
      for (int jj = 0; jj < 4; ++jj) {
        const u16 a = sm[q * 8 + 2 * jj][nt * 16 + rm];
        const u16 b = sm[q * 8 + 2 * jj + 1][nt * 16 + rm];
        w4[jj] = (u32)a | ((u32)b << 16);
      }
      o.x = w4[0]; o.y = w4[1]; o.z = w4[2]; o.w = w4[3];
      *(uint4*)(wbuf + (size_t)(NW1 + NW2) * 8 +
                ((size_t)(kk * NTH + nt) * KSH + ks) * 512 + lane * 8) = o;
    }
  } else {  // ---- tables ----
    __shared__ int wcnt[4][K];
    __shared__ int pre[4][K];
    __shared__ int cofs[K + 1];
    const int a = assign[tid];
    const u64 below = (1ull << lane) - 1ull;
    int myrank = 0;
#pragma unroll
    for (int k = 0; k < K; ++k) {
      const u64 m = __ballot(a == k);
      if (a == k) myrank = (int)__popcll(m & below);
      if (lane == 0) wcnt[wid][k] = (int)__popcll(m);
    }
    __syncthreads();
    if (tid == 0) {
      int tot[K];
      for (int k = 0; k < K; ++k) {
        int s = 0;
        for (int ww = 0; ww < 4; ++ww) {
          pre[ww][k] = s;
          s += wcnt[ww][k];
        }
        tot[k] = s;
      }
      cofs[0] = 0;
      for (int k = 0; k < K; ++k) cofs[k + 1] = cofs[k] + tot[k];
      for (int k = 0; k <= K; ++k) meta[512 + k] = cofs[k];
    }
    __syncthreads();
    const int pos = cofs[a] + pre[wid][a] + myrank;
    meta[256 + pos] = tid;  // chlist
    meta[520 + tid] = pos;  // ipos (inverse chlist)
    int k = 0;
    while (k < K - 1 && tid >= cofs[k + 1]) ++k;
    meta[tid] = (k << 16) | ((tid - cofs[k]) * TM);
  }
}

// ---- main kernel: 16 waves/block, 1 block/CU, 32x32x16 MFMA ----
__global__ __launch_bounds__(1024, 4) void mlp_mfma(
    const float* __restrict__ x, const float* __restrict__ rev_w,
    const float* __restrict__ rev_b, const float* __restrict__ b1,
    const float* __restrict__ b2, const float* __restrict__ bh,
    const int* __restrict__ meta, const u16* __restrict__ wbuf) {
  __shared__ __align__(16) u16 zb[TM][ZBS];  // 23.0 KB
  __shared__ __align__(16) u16 Hsh[TM][HS];  // 66.0 KB
  __shared__ float s_mean[TM], s_std[TM], s_rw[TM], s_rb[TM];
  __shared__ int s_b[TM], s_p[TM];

  const int tid = threadIdx.x;
  const int wid = tid >> 6;  // 0..15
  const int lane = tid & 63;
  const int q = lane >> 4, rm = lane & 15;    // head (16x16)
  const int q2 = lane >> 5, n32 = lane & 31;  // 32x32

  const int swz = (blockIdx.x & 7) * 32 + (blockIdx.x >> 3);
  const int info = meta[swz];
  const int kcl = info >> 16;
  const int rstart = info & 0xffff;
  const int cofs = meta[512 + kcl];
  const int cnt = meta[512 + kcl + 1] - cofs;

  const u16* w1b = wbuf;
  const u16* w2b = wbuf + (size_t)NW1 * 8;
  const u16* whb = wbuf + (size_t)(NW1 + NW2) * 8;

  // L1: preload layer-0 phase-1 ring FIRST (front starts at t=0,
  // overlaps RevIN's x reads + reduction). Zero extra live regs: a1
  // is allocated anyway.
  bf16x8 a1[2][D1];
  {
    const u16* b0 = w1b + (size_t)(kcl * NL) * W1FRAGS * 8 +
                    (size_t)(wid * 2) * TS1 + lane * 8;
#pragma unroll
    for (int t = 0; t < 2; ++t)
#pragma unroll
      for (int s = 0; s < D1; ++s)
        a1[t][s] = *(const bf16x8*)(b0 + (size_t)t * TS1 + s * 512);
  }

  // ---- RevIN: 2 rows per wave ----
  for (int i = 0; i < 2; ++i) {
    const int t = wid * 2 + i;
    const int ri = rstart + t;
    const int b = ri / cnt;
    const int c = meta[256 + cofs + (ri % cnt)];
    const float* xrow = x + (size_t)(b * C + c) * L;
    float v[6], s = 0.f, s2 = 0.f;
#pragma unroll
    for (int jj = 0; jj < 6; ++jj) {
      const int j = lane + jj * 64;
      v[jj] = (j < L) ? xrow[j] : 0.f;
      s += v[jj];
      s2 += v[jj] * v[jj];
    }
#pragma unroll
    for (int off = 32; off > 0; off >>= 1) {
      s += __shfl_down(s, off);
      s2 += __shfl_down(s2, off);
    }
    s = __shfl(s, 0);
    s2 = __shfl(s2, 0);
    const float mean = s * (1.f / L);
    const float var = s2 * (1.f / L) - mean * mean;
    const float stdv = sqrtf(var + 1e-5f);
    const float rstd = 1.f / stdv;
    const float rw = rev_w[c], rb_ = rev_b[c];
#pragma unroll
    for (int jj = 0; jj < 6; ++jj) {
      const int j = lane + jj * 64;
      if (j < L) zb[t][j] = f2bf((v[jj] - mean) * rstd * rw + rb_);
    }
    if (lane < LP - L) zb[t][L + lane] = 0;
    if (lane == 0) {
      s_mean[t] = mean;
      s_std[t] = stdv;
      s_rw[t] = rw;
      s_rb[t] = rb_;
      s_b[t] = b;
      s_p[t] = cofs + (ri % cnt);  // cluster-packed channel position
    }
  }
  __syncthreads();  // zb ready

  // ---- fp32 residual master (D32 layout), waves 0..10 own l-tile wid ----
  f32x16 zm;
#pragma unroll
  for (int i = 0; i < 16; ++i) zm[i] = 0.f;
  if (wid < LT2) {
#pragma unroll
    for (int g = 0; g < 4; ++g) {
      const uint2 zw = *(const uint2*)&zb[n32][32 * wid + 8 * g + 4 * q2];
      zm[4 * g + 0] = bf2f((u16)zw.x);
      zm[4 * g + 1] = bf2f((u16)(zw.x >> 16));
      zm[4 * g + 2] = bf2f((u16)zw.y);
      zm[4 * g + 3] = bf2f((u16)(zw.y >> 16));
    }
  }

  for (int l = 0; l < NL; ++l) {
    const int kl = kcl * NL + l;
    const u16* W1f = w1b + (size_t)kl * W1FRAGS * 8;
    const u16* W2f = w2b + (size_t)kl * W2FRAGS * 8;
    const float* b1p = b1 + kl * DFF;
    const float* b2p = b2 + kl * L;
    const u16* base1 = W1f + (size_t)(wid * 2) * TS1 + lane * 8;

    // -- phase 1: H = relu(z @ W1 + b1); 2 d-tiles/wave, depth-D1 ring
    f32x16 acc[2];
#pragma unroll
    for (int t = 0; t < 2; ++t)
#pragma unroll
      for (int i = 0; i < 16; ++i) acc[t][i] = 0.f;
#pragma unroll
    for (int ks = 0; ks < KT1; ++ks) {
      const bf16x8 zf = *(const bf16x8*)&zb[n32][ks * 16 + q2 * 8];
#pragma unroll
      for (int t = 0; t < 2; ++t)
        acc[t] = __builtin_amdgcn_mfma_f32_32x32x16_bf16(a1[t][ks % D1], zf,
                                                         acc[t], 0, 0, 0);
      if (ks + D1 < KT1) {
#pragma unroll
        for (int t = 0; t < 2; ++t)
          a1[t][ks % D1] =
              *(const bf16x8*)(base1 + (size_t)t * TS1 + (ks + D1) * 512);
      }
    }
    // epilogue: bias+relu, write Hsh[sample][d]
#pragma unroll
    for (int t = 0; t < 2; ++t) {
      const int dt = wid * 2 + t;
#pragma unroll
      for (int g = 0; g < 4; ++g) {
        const int db = dt * 32 + 8 * g + 4 * q2;
        const float4 bq = *(const float4*)(b1p + db);
        uint2 hw;
        hw.x = pack2(fmaxf(acc[t][4 * g + 0] + bq.x, 0.f),
                     fmaxf(acc[t][4 * g + 1] + bq.y, 0.f));
        hw.y = pack2(fmaxf(acc[t][4 * g + 2] + bq.z, 0.f),
                     fmaxf(acc[t][4 * g + 3] + bq.w, 0.f));
        *(uint2*)&Hsh[n32][db] = hw;
      }
    }

    // preload phase-2 ring (depth D2) after epilogue (acc dead), before
    // the barrier (global-only; r18 proved before-epilogue spills)
    bf16x8 a2[D2];
    const u16* base2 = W2f + (size_t)wid * TS2 + lane * 8;
    if (wid < LT2) {
#pragma unroll
      for (int s = 0; s < D2; ++s)
        a2[s] = *(const bf16x8*)(base2 + s * 512);
    }
    __syncthreads();  // Hsh ready

    // -- phase 2: zm += H @ W2; 1 l-tile/wave (waves 0..10), depth-D2 ring
    if (wid < LT2) {
#pragma unroll
      for (int ks = 0; ks < KT2; ++ks) {
        const bf16x8 hf = *(const bf16x8*)&Hsh[n32][ks * 16 + q2 * 8];
        zm = __builtin_amdgcn_mfma_f32_32x32x16_bf16(a2[ks % D2], hf, zm, 0, 0,
                                                     0);
        if (ks + D2 < KT2)
          a2[ks % D2] = *(const bf16x8*)(base2 + (ks + D2) * 512);
      }
      // epilogue: zm += b2, refresh bf16 zb
#pragma unroll
      for (int g = 0; g < 4; ++g) {
        const int lc = 32 * wid + 8 * g + 4 * q2;
        if (lc < L) {
          const float4 bq = *(const float4*)(b2p + lc);
          zm[4 * g + 0] += bq.x;
          zm[4 * g + 1] += bq.y;
          zm[4 * g + 2] += bq.z;
          zm[4 * g + 3] += bq.w;
        }
        uint2 zw;
        zw.x = pack2(zm[4 * g + 0], zm[4 * g + 1]);
        zw.y = pack2(zm[4 * g + 2], zm[4 * g + 3]);
        *(uint2*)&zb[n32][lc] = zw;
      }
    }

    // preload next layer's phase-1 ring before the barrier (global-only)
    if (l + 1 < NL) {
      const u16* nb = w1b + (size_t)(kl + 1) * W1FRAGS * 8 +
                      (size_t)(wid * 2) * TS1 + lane * 8;
#pragma unroll
      for (int t = 0; t < 2; ++t)
#pragma unroll
        for (int s = 0; s < D1; ++s)
          a1[t][s] = *(const bf16x8*)(nb + (size_t)t * TS1 + s * 512);
    }
    __syncthreads();  // zb final for this layer
  }

  // ---- head (16x16 path): g_y[b][o][p] = denorm(z @ Wh + bh), packed ----
  if (wid < NTH) {
    const u16* Whf =
        whb + (size_t)kcl * WHFRAGS * 8 + (size_t)wid * THS + lane * 8;
    f32x4 acc0 = {0.f, 0.f, 0.f, 0.f}, acc1 = {0.f, 0.f, 0.f, 0.f};
    for (int ks = 0; ks < KSH; ++ks) {
      const bf16x8 af = *(const bf16x8*)(Whf + ks * 512);
      const bf16x8 zf0 = *(const bf16x8*)&zb[rm][ks * 32 + q * 8];
      const bf16x8 zf1 = *(const bf16x8*)&zb[rm + 16][ks * 32 + q * 8];
      acc0 = __builtin_amdgcn_mfma_f32_16x16x32_bf16(af, zf0, acc0, 0, 0, 0);
      acc1 = __builtin_amdgcn_mfma_f32_16x16x32_bf16(af, zf1, acc1, 0, 0, 0);
    }
    const float4 bq = *(const float4*)(bh + kcl * O + wid * 16 + q * 4);
    const float bqa[4] = {bq.x, bq.y, bq.z, bq.w};
#pragma unroll
    for (int rg = 0; rg < 2; ++rg) {
      const int row = rm + 16 * rg;
      const float mean = s_mean[row], stdv = s_std[row];
      const float rw = s_rw[row], rb_ = s_rb[row];
      const int ob = s_b[row], pp = s_p[row];
      const f32x4 acc = rg ? acc1 : acc0;
#pragma unroll
      for (int gg = 0; gg < 4; ++gg) {
        const int o = wid * 16 + q * 4 + gg;
        const float v = acc[gg] + bqa[gg];
        // packed-channel layout: consecutive rows (rm) -> consecutive pp
        // -> full-line, single-writer 64B stores
        g_y[((size_t)ob * O + o) * C + pp] = (v - rb_) / rw * stdv + mean;
      }
    }
  }
}

// ---- permute g_y (cluster-packed channels) -> out[b][o][c] ----
__global__ __launch_bounds__(1024) void scatter_out(
    const int* __restrict__ meta, float* __restrict__ out) {
  const int row = blockIdx.x * 4 + (threadIdx.x >> 8);  // (b*O+o)
  const int c = threadIdx.x & 255;
  const int p = meta[520 + c];  // packed position of channel c
  out[(size_t)row * C + c] = g_y[(size_t)row * C + p];
}

extern "C" void kernel_launch(void* const* d_in, const int* in_sizes, int n_in,
                              void* d_out, int out_size, void* d_ws,
                              size_t ws_size, hipStream_t stream) {
  const float* x = (const float*)d_in[0];
  const float* rev_w = (const float*)d_in[1];
  const float* rev_b = (const float*)d_in[2];
  const float* W1 = (const float*)d_in[3];
  const float* b1 = (const float*)d_in[4];
  const float* W2 = (const float*)d_in[5];
  const float* b2 = (const float*)d_in[6];
  const float* Wh = (const float*)d_in[7];
  const float* bh = (const float*)d_in[8];
  const int* assign = (const int*)d_in[9];
  float* out = (float*)d_out;

  int* meta = (int*)d_ws;                  // ~3.1 KB
  u16* wbuf = (u16*)((char*)d_ws + 4096);  // 11.6 MB bf16 fragments

  prep<<<NPREP, 256, 0, stream>>>(assign, W1, W2, Wh, meta, wbuf);
  mlp_mfma<<<NTILES, 1024, 0, stream>>>(x, rev_w, rev_b, b1, b2, bh, meta,
                                        wbuf);
  scatter_out<<<(B * O) / 4, 1024, 0, stream>>>(meta, out);
}